// Round 1
// baseline (401.853 us; speedup 1.0000x reference)
//
#include <hip/hip_runtime.h>

typedef __bf16 bf16;
typedef bf16 bf16x2 __attribute__((ext_vector_type(2)));
typedef bf16 bf16x4 __attribute__((ext_vector_type(4)));
typedef bf16 bf16x8 __attribute__((ext_vector_type(8)));
typedef float f32x4 __attribute__((ext_vector_type(4)));
typedef float f32x16 __attribute__((ext_vector_type(16)));
typedef int i32x2 __attribute__((ext_vector_type(2)));

#define SEQ 256
#define DH  32
#define VT_PAD 264   // bf16 row stride 528B = 33*16B -> 16B-col stride 1 mod 8 (4 lanes/col baseline)
#define KB_PAD 40    // bf16 row stride  80B =  5*16B -> 16B-col stride 5 mod 8 (conflict-free b128)

// pack two f32 -> one dword of 2 bf16 (compiler emits v_cvt_pk_bf16_f32)
static __device__ __forceinline__ int pk2(float a, float b) {
    bf16x2 t; t[0] = (bf16)a; t[1] = (bf16)b;
    int r; __builtin_memcpy(&r, &t, sizeof(r)); return r;
}

// S^T = K*Q^T with 32x32x16 MFMAs (M=t keys, N=s queries, K=d).
// C layout: col = s = lane&31, row = t = (reg&3) + 8*(reg>>2) + 4*(lane>>5).
// P->PV A-frag (row s = lane&31, k = t = hi*8+j) built in-register:
//   A_g = pk(p[4g..4g+3]) covers t = 8g+4hi+{0..3};
//   permlane32_swap(A_g0,A_g1) -> dw0/dw2, swap(A_g0.y,A_g1.y) -> dw1/dw3 of the frag.
__global__ __launch_bounds__(256, 4) void attn_mfma_kernel(
    const float* __restrict__ q,
    const float* __restrict__ k,
    const float* __restrict__ v,
    const float* __restrict__ mask_bias,   // [N][SEQ]
    const float* __restrict__ tri_bias,    // [H][SEQ][SEQ]
    float* __restrict__ out)
{
    __shared__ bf16 Vt[DH][VT_PAD];    // V^T: Vt[d][t], 16896 B
    __shared__ bf16 Kb[SEQ][KB_PAD];   // K:   Kb[t][d], 20480 B
    __shared__ float Ml[SEQ];          // mask*log2e,     1024 B

    const int tid  = threadIdx.x;
    const int wave = tid >> 6;
    const int lane = tid & 63;
    const int l31  = lane & 31;
    const int hi   = lane >> 5;

    const int inst = blockIdx.x;       // n*4 + h
    const int n    = inst >> 2;
    const int h    = inst & 3;

    const float* qb = q + (size_t)inst * SEQ * DH;
    const float* kb = k + (size_t)inst * SEQ * DH;
    const float* vb = v + (size_t)inst * SEQ * DH;
    const float* mb = mask_bias + (size_t)n * SEQ;
    const float* tb = tri_bias + (size_t)h * SEQ * SEQ;

    const float K1    = 0.17677669529663687f * 1.44269504088896f; // scale*log2e
    const float LOG2E = 1.44269504088896f;

    const int sbase = wave * 64;       // wave owns 64 queries = 2 stiles of 32

    // per-lane tri row pointers (lane reads row s = sbase + st*32 + l31, cols t0+4hi..)
    const float* trow0 = tb + (size_t)(sbase + l31) * SEQ + 4 * hi;
    const float* trow1 = trow0 + 32 * SEQ;

    // ---- prefetch tri stile0, chunk 0 (issue before staging so it's in flight) ----
    f32x4 tpre0[4];
    #pragma unroll
    for (int g = 0; g < 4; ++g)
        tpre0[g] = *(const f32x4*)(trow0 + 8 * g);

    // ---- Q b-frags: qf[st][dh] = Q[sbase+st*32+l31][dh*16 + hi*8 .. +7] ----
    bf16x8 qf[2][2];
    #pragma unroll
    for (int st = 0; st < 2; ++st)
        #pragma unroll
        for (int dh = 0; dh < 2; ++dh) {
            const float* p = qb + (size_t)(sbase + st * 32 + l31) * DH + dh * 16 + hi * 8;
            f32x4 a = ((const f32x4*)p)[0];
            f32x4 b = ((const f32x4*)p)[1];
            bf16x8 f;
            f[0]=(bf16)a[0]; f[1]=(bf16)a[1]; f[2]=(bf16)a[2]; f[3]=(bf16)a[3];
            f[4]=(bf16)b[0]; f[5]=(bf16)b[1]; f[6]=(bf16)b[2]; f[7]=(bf16)b[3];
            qf[st][dh] = f;
        }

    // ---- stage V^T (bf16), K (bf16), mask*log2e into LDS ----
    #pragma unroll
    for (int i = 0; i < 8; ++i) {
        int idx = i * 256 + tid;       // float4 index: t = idx>>3, d-group = idx&7
        int t   = idx >> 3;
        int d4  = (idx & 7) * 4;
        f32x4 tv = ((const f32x4*)vb)[idx];
        Vt[d4 + 0][t] = (bf16)tv[0];
        Vt[d4 + 1][t] = (bf16)tv[1];
        Vt[d4 + 2][t] = (bf16)tv[2];
        Vt[d4 + 3][t] = (bf16)tv[3];
        f32x4 tk = ((const f32x4*)kb)[idx];
        bf16x4 kk;
        kk[0]=(bf16)tk[0]; kk[1]=(bf16)tk[1]; kk[2]=(bf16)tk[2]; kk[3]=(bf16)tk[3];
        *(bf16x4*)&Kb[t][d4] = kk;     // 8B write, aligned
    }
    Ml[tid] = mb[tid] * LOG2E;
    __syncthreads();

    f32x16 oacc0 = {}, oacc1 = {};
    float lp0 = 0.f, lp1 = 0.f;
    const f32x16 z16 = {};

    // ---- main loop: 8 chunks of 32 keys ----
    #pragma unroll
    for (int c = 0; c < 8; ++c) {
        const int tb0 = c * 32;

        // issue tri stile1 loads for this chunk (consumed after QK1, ~400cy cover)
        f32x4 t1g[4];
        #pragma unroll
        for (int g = 0; g < 4; ++g)
            t1g[g] = *(const f32x4*)(trow1 + tb0 + 8 * g);

        // K a-frags from LDS: Kb[tb0+l31][dh*16 + hi*8 .. +7]
        bf16x8 kf0 = *(const bf16x8*)&Kb[tb0 + l31][hi * 8];
        bf16x8 kf1 = *(const bf16x8*)&Kb[tb0 + l31][16 + hi * 8];

        // mask*log2e (LDS broadcast): t = tb0 + 8g + 4hi + {0..3}
        f32x4 mkv[4];
        #pragma unroll
        for (int g = 0; g < 4; ++g)
            mkv[g] = *(const f32x4*)&Ml[tb0 + 8 * g + 4 * hi];

        // ================= stile 0 =================
        f32x16 cf = __builtin_amdgcn_mfma_f32_32x32x16_bf16(kf0, qf[0][0], z16, 0, 0, 0);
        cf = __builtin_amdgcn_mfma_f32_32x32x16_bf16(kf1, qf[0][1], cf, 0, 0, 0);

        int A[8];
        #pragma unroll
        for (int g = 0; g < 4; ++g) {
            float p0 = __builtin_amdgcn_exp2f(fmaf(cf[4*g+0], K1, fmaf(tpre0[g][0], LOG2E, mkv[g][0])));
            float p1 = __builtin_amdgcn_exp2f(fmaf(cf[4*g+1], K1, fmaf(tpre0[g][1], LOG2E, mkv[g][1])));
            float p2 = __builtin_amdgcn_exp2f(fmaf(cf[4*g+2], K1, fmaf(tpre0[g][2], LOG2E, mkv[g][2])));
            float p3 = __builtin_amdgcn_exp2f(fmaf(cf[4*g+3], K1, fmaf(tpre0[g][3], LOG2E, mkv[g][3])));
            lp0 += (p0 + p1) + (p2 + p3);
            A[2*g]   = pk2(p0, p1);
            A[2*g+1] = pk2(p2, p3);
        }

        // prefetch tri stile0 for NEXT chunk (regs free now; full chunk of cover)
        if (c < 7) {
            #pragma unroll
            for (int g = 0; g < 4; ++g)
                tpre0[g] = *(const f32x4*)(trow0 + tb0 + 32 + 8 * g);
        }

        i32x2 s0 = __builtin_amdgcn_permlane32_swap(A[0], A[2], false, false);
        i32x2 s1 = __builtin_amdgcn_permlane32_swap(A[1], A[3], false, false);
        i32x2 s2 = __builtin_amdgcn_permlane32_swap(A[4], A[6], false, false);
        i32x2 s3 = __builtin_amdgcn_permlane32_swap(A[5], A[7], false, false);
        union { int i[4]; bf16x8 v; } pa0, pa1;
        pa0.i[0] = s0[0]; pa0.i[1] = s1[0]; pa0.i[2] = s0[1]; pa0.i[3] = s1[1]; // t-local 0..15
        pa1.i[0] = s2[0]; pa1.i[1] = s3[0]; pa1.i[2] = s2[1]; pa1.i[3] = s3[1]; // t-local 16..31

        // V b-frags from LDS: Vt[l31][tb0 + tau*16 + hi*8 .. +7]
        bf16x8 vf0 = *(const bf16x8*)&Vt[l31][tb0 + hi * 8];
        bf16x8 vf1 = *(const bf16x8*)&Vt[l31][tb0 + 16 + hi * 8];

        oacc0 = __builtin_amdgcn_mfma_f32_32x32x16_bf16(pa0.v, vf0, oacc0, 0, 0, 0);
        oacc0 = __builtin_amdgcn_mfma_f32_32x32x16_bf16(pa1.v, vf1, oacc0, 0, 0, 0);

        // ================= stile 1 =================
        cf = __builtin_amdgcn_mfma_f32_32x32x16_bf16(kf0, qf[1][0], z16, 0, 0, 0);
        cf = __builtin_amdgcn_mfma_f32_32x32x16_bf16(kf1, qf[1][1], cf, 0, 0, 0);

        #pragma unroll
        for (int g = 0; g < 4; ++g) {
            float p0 = __builtin_amdgcn_exp2f(fmaf(cf[4*g+0], K1, fmaf(t1g[g][0], LOG2E, mkv[g][0])));
            float p1 = __builtin_amdgcn_exp2f(fmaf(cf[4*g+1], K1, fmaf(t1g[g][1], LOG2E, mkv[g][1])));
            float p2 = __builtin_amdgcn_exp2f(fmaf(cf[4*g+2], K1, fmaf(t1g[g][2], LOG2E, mkv[g][2])));
            float p3 = __builtin_amdgcn_exp2f(fmaf(cf[4*g+3], K1, fmaf(t1g[g][3], LOG2E, mkv[g][3])));
            lp1 += (p0 + p1) + (p2 + p3);
            A[2*g]   = pk2(p0, p1);
            A[2*g+1] = pk2(p2, p3);
        }

        s0 = __builtin_amdgcn_permlane32_swap(A[0], A[2], false, false);
        s1 = __builtin_amdgcn_permlane32_swap(A[1], A[3], false, false);
        s2 = __builtin_amdgcn_permlane32_swap(A[4], A[6], false, false);
        s3 = __builtin_amdgcn_permlane32_swap(A[5], A[7], false, false);
        union { int i[4]; bf16x8 v; } pb0, pb1;
        pb0.i[0] = s0[0]; pb0.i[1] = s1[0]; pb0.i[2] = s0[1]; pb0.i[3] = s1[1];
        pb1.i[0] = s2[0]; pb1.i[1] = s3[0]; pb1.i[2] = s2[1]; pb1.i[3] = s3[1];

        oacc1 = __builtin_amdgcn_mfma_f32_32x32x16_bf16(pb0.v, vf0, oacc1, 0, 0, 0);
        oacc1 = __builtin_amdgcn_mfma_f32_32x32x16_bf16(pb1.v, vf1, oacc1, 0, 0, 0);
    }

    // ---- softmax denominators: hi-half reduce, then normalize + store ----
    lp0 += __shfl_xor(lp0, 32);
    lp1 += __shfl_xor(lp1, 32);
    const float li0 = 1.0f / lp0;      // valid for s = sbase + l31 (both hi halves)
    const float li1 = 1.0f / lp1;      // valid for s = sbase + 32 + l31

    float* ob = out + (size_t)inst * SEQ * DH;
    #pragma unroll
    for (int r = 0; r < 16; ++r) {
        const int srow = (r & 3) + 8 * (r >> 2) + 4 * hi;
        float i0 = __shfl(li0, srow);  // 1/l for row srow lives in lane srow
        float i1 = __shfl(li1, srow);
        ob[(size_t)(sbase + srow) * DH + l31]      = oacc0[r] * i0;
        ob[(size_t)(sbase + 32 + srow) * DH + l31] = oacc1[r] * i1;
    }
}

extern "C" void kernel_launch(void* const* d_in, const int* in_sizes, int n_in,
                              void* d_out, int out_size, void* d_ws, size_t ws_size,
                              hipStream_t stream) {
    const float* q    = (const float*)d_in[0];
    const float* k    = (const float*)d_in[1];
    const float* v    = (const float*)d_in[2];
    const float* mask = (const float*)d_in[3];
    const float* tri  = (const float*)d_in[4];
    float* out = (float*)d_out;

    attn_mfma_kernel<<<dim3(256 * 4), dim3(256), 0, stream>>>(q, k, v, mask, tri, out);
}

// Round 2
// 158.454 us; speedup vs baseline: 2.5361x; 2.5361x over previous
//
#include <hip/hip_runtime.h>

typedef __bf16 bf16;
typedef bf16 bf16x2 __attribute__((ext_vector_type(2)));
typedef bf16 bf16x4 __attribute__((ext_vector_type(4)));
typedef bf16 bf16x8 __attribute__((ext_vector_type(8)));
typedef float f32x4 __attribute__((ext_vector_type(4)));
typedef float f32x16 __attribute__((ext_vector_type(16)));
typedef int i32x2 __attribute__((ext_vector_type(2)));
typedef int i32x4 __attribute__((ext_vector_type(4)));

#define SEQ 256
#define DH  32
#define VT_PAD 264   // bf16 row stride 528B = 33*16B
#define KB_PAD 40    // bf16 row stride  80B =  5*16B -> conflict-free b128 column reads

// pack two f32 -> one dword of 2 bf16 (v_cvt_pk_bf16_f32); no unions, no memcpy
static __device__ __forceinline__ int pk2(float a, float b) {
    bf16x2 t; t[0] = (bf16)a; t[1] = (bf16)b;
    return __builtin_bit_cast(int, t);
}

// One C-register group g of the 32x32 QK^T output -> exp2 -> two packed dwords
// covering t = 8g+4hi+{0..3}. All indices compile-time (G template param).
template<int G>
static __device__ __forceinline__ i32x2 pgrp(f32x16 cf, f32x4 tg, f32x4 mk, float& lp) {
    constexpr float K1    = 0.17677669529663687f * 1.44269504088896f; // sm_scale*log2e
    constexpr float LOG2E = 1.44269504088896f;
    float p0 = __builtin_amdgcn_exp2f(fmaf(cf[4*G+0], K1, fmaf(tg[0], LOG2E, mk[0])));
    float p1 = __builtin_amdgcn_exp2f(fmaf(cf[4*G+1], K1, fmaf(tg[1], LOG2E, mk[1])));
    float p2 = __builtin_amdgcn_exp2f(fmaf(cf[4*G+2], K1, fmaf(tg[2], LOG2E, mk[2])));
    float p3 = __builtin_amdgcn_exp2f(fmaf(cf[4*G+3], K1, fmaf(tg[3], LOG2E, mk[3])));
    lp += (p0 + p1) + (p2 + p3);
    i32x2 r; r[0] = pk2(p0, p1); r[1] = pk2(p2, p3);
    return r;
}

// 4 permlane32_swap -> two PV A-frags (t-local 0..15 and 16..31), pure vector ops
static __device__ __forceinline__ void frags(i32x2 a0, i32x2 a1, i32x2 a2, i32x2 a3,
                                             bf16x8& f0, bf16x8& f1) {
    i32x2 s0 = __builtin_amdgcn_permlane32_swap(a0[0], a1[0], false, false);
    i32x2 s1 = __builtin_amdgcn_permlane32_swap(a0[1], a1[1], false, false);
    i32x2 s2 = __builtin_amdgcn_permlane32_swap(a2[0], a3[0], false, false);
    i32x2 s3 = __builtin_amdgcn_permlane32_swap(a2[1], a3[1], false, false);
    i32x4 w0 = {s0[0], s1[0], s0[1], s1[1]};
    i32x4 w1 = {s2[0], s3[0], s2[1], s3[1]};
    f0 = __builtin_bit_cast(bf16x8, w0);
    f1 = __builtin_bit_cast(bf16x8, w1);
}

// S^T = K*Q^T with 32x32x16 MFMAs (M=t keys, N=s queries).
// C layout: col = s = lane&31, row = t = (reg&3) + 8*(reg>>2) + 4*(lane>>5).
__global__ __launch_bounds__(256, 2) void attn_mfma_kernel(
    const float* __restrict__ q,
    const float* __restrict__ k,
    const float* __restrict__ v,
    const float* __restrict__ mask_bias,   // [N][SEQ]
    const float* __restrict__ tri_bias,    // [H][SEQ][SEQ]
    float* __restrict__ out)
{
    __shared__ bf16 Vt[DH][VT_PAD];    // V^T: Vt[d][t], 16896 B
    __shared__ bf16 Kb[SEQ][KB_PAD];   // K:   Kb[t][d], 20480 B
    __shared__ float Ml[SEQ];          // mask*log2e,     1024 B

    const int tid  = threadIdx.x;
    const int wave = tid >> 6;
    const int lane = tid & 63;
    const int l31  = lane & 31;
    const int hi   = lane >> 5;

    const int inst = blockIdx.x;       // n*4 + h
    const int n    = inst >> 2;
    const int h    = inst & 3;

    const float* qb = q + (size_t)inst * SEQ * DH;
    const float* kb = k + (size_t)inst * SEQ * DH;
    const float* vb = v + (size_t)inst * SEQ * DH;
    const float* mb = mask_bias + (size_t)n * SEQ;
    const float* tb = tri_bias + (size_t)h * SEQ * SEQ;

    constexpr float LOG2E = 1.44269504088896f;

    const int sbase = wave * 64;       // wave owns 64 queries = 2 stiles of 32

    // per-lane tri row pointers: lane reads row s = sbase + st*32 + l31, cols +4hi
    const float* trow0 = tb + (size_t)(sbase + l31) * SEQ + 4 * hi;
    const float* trow1 = trow0 + 32 * SEQ;

    // prefetch tri stile0 chunk0 (in flight across staging)
    f32x4 tp0 = *(const f32x4*)(trow0 + 0);
    f32x4 tp1 = *(const f32x4*)(trow0 + 8);
    f32x4 tp2 = *(const f32x4*)(trow0 + 16);
    f32x4 tp3 = *(const f32x4*)(trow0 + 24);

    // Q b-frags: qfSD = Q[sbase+S*32+l31][D*16 + hi*8 .. +7]
    bf16x8 qf00, qf01, qf10, qf11;
    {
        const float* p0 = qb + (size_t)(sbase + l31) * DH + hi * 8;
        const float* p1 = qb + (size_t)(sbase + 32 + l31) * DH + hi * 8;
        f32x4 a, b;
        bf16x8 f;
        a = ((const f32x4*)p0)[0]; b = ((const f32x4*)p0)[1];
        f[0]=(bf16)a[0]; f[1]=(bf16)a[1]; f[2]=(bf16)a[2]; f[3]=(bf16)a[3];
        f[4]=(bf16)b[0]; f[5]=(bf16)b[1]; f[6]=(bf16)b[2]; f[7]=(bf16)b[3];
        qf00 = f;
        a = ((const f32x4*)(p0 + 16))[0]; b = ((const f32x4*)(p0 + 16))[1];
        f[0]=(bf16)a[0]; f[1]=(bf16)a[1]; f[2]=(bf16)a[2]; f[3]=(bf16)a[3];
        f[4]=(bf16)b[0]; f[5]=(bf16)b[1]; f[6]=(bf16)b[2]; f[7]=(bf16)b[3];
        qf01 = f;
        a = ((const f32x4*)p1)[0]; b = ((const f32x4*)p1)[1];
        f[0]=(bf16)a[0]; f[1]=(bf16)a[1]; f[2]=(bf16)a[2]; f[3]=(bf16)a[3];
        f[4]=(bf16)b[0]; f[5]=(bf16)b[1]; f[6]=(bf16)b[2]; f[7]=(bf16)b[3];
        qf10 = f;
        a = ((const f32x4*)(p1 + 16))[0]; b = ((const f32x4*)(p1 + 16))[1];
        f[0]=(bf16)a[0]; f[1]=(bf16)a[1]; f[2]=(bf16)a[2]; f[3]=(bf16)a[3];
        f[4]=(bf16)b[0]; f[5]=(bf16)b[1]; f[6]=(bf16)b[2]; f[7]=(bf16)b[3];
        qf11 = f;
    }

    // stage V^T (bf16), K (bf16), mask*log2e into LDS
    #pragma unroll
    for (int i = 0; i < 8; ++i) {
        int idx = i * 256 + tid;       // float4 index: t = idx>>3, d-group = idx&7
        int t   = idx >> 3;
        int d4  = (idx & 7) * 4;
        f32x4 tv = ((const f32x4*)vb)[idx];
        Vt[d4 + 0][t] = (bf16)tv[0];
        Vt[d4 + 1][t] = (bf16)tv[1];
        Vt[d4 + 2][t] = (bf16)tv[2];
        Vt[d4 + 3][t] = (bf16)tv[3];
        f32x4 tk = ((const f32x4*)kb)[idx];
        bf16x4 kk;
        kk[0]=(bf16)tk[0]; kk[1]=(bf16)tk[1]; kk[2]=(bf16)tk[2]; kk[3]=(bf16)tk[3];
        *(bf16x4*)&Kb[t][d4] = kk;     // 8B aligned write
    }
    Ml[tid] = mb[tid] * LOG2E;
    __syncthreads();

    f32x16 oacc0 = {}, oacc1 = {};
    float lp0 = 0.f, lp1 = 0.f;
    const f32x16 z16 = {};

    // main loop: 8 chunks of 32 keys (NOT unrolled: keep live ranges short)
    for (int c = 0; c < 8; ++c) {
        const int tb0 = c * 32;

        // issue tri stile1 loads now (consumed after QK1 -> latency covered)
        f32x4 u0 = *(const f32x4*)(trow1 + tb0 + 0);
        f32x4 u1 = *(const f32x4*)(trow1 + tb0 + 8);
        f32x4 u2 = *(const f32x4*)(trow1 + tb0 + 16);
        f32x4 u3 = *(const f32x4*)(trow1 + tb0 + 24);

        // K a-frags from LDS: Kb[tb0+l31][dh*16 + hi*8 .. +7]
        bf16x8 kf0 = *(const bf16x8*)&Kb[tb0 + l31][hi * 8];
        bf16x8 kf1 = *(const bf16x8*)&Kb[tb0 + l31][16 + hi * 8];

        // mask*log2e (LDS broadcast): t = tb0 + 8g + 4hi + {0..3}
        f32x4 mk0 = *(const f32x4*)&Ml[tb0 +  0 + 4 * hi];
        f32x4 mk1 = *(const f32x4*)&Ml[tb0 +  8 + 4 * hi];
        f32x4 mk2 = *(const f32x4*)&Ml[tb0 + 16 + 4 * hi];
        f32x4 mk3 = *(const f32x4*)&Ml[tb0 + 24 + 4 * hi];

        // ============ stile 0 ============
        f32x16 cf = __builtin_amdgcn_mfma_f32_32x32x16_bf16(kf0, qf00, z16, 0, 0, 0);
        cf = __builtin_amdgcn_mfma_f32_32x32x16_bf16(kf1, qf01, cf, 0, 0, 0);

        i32x2 a0 = pgrp<0>(cf, tp0, mk0, lp0);
        i32x2 a1 = pgrp<1>(cf, tp1, mk1, lp0);
        i32x2 a2 = pgrp<2>(cf, tp2, mk2, lp0);
        i32x2 a3 = pgrp<3>(cf, tp3, mk3, lp0);

        // prefetch tri stile0 for NEXT chunk (full chunk of latency cover)
        if (c < 7) {
            tp0 = *(const f32x4*)(trow0 + tb0 + 32);
            tp1 = *(const f32x4*)(trow0 + tb0 + 40);
            tp2 = *(const f32x4*)(trow0 + tb0 + 48);
            tp3 = *(const f32x4*)(trow0 + tb0 + 56);
        }

        bf16x8 pa0, pa1;
        frags(a0, a1, a2, a3, pa0, pa1);

        // V b-frags from LDS: Vt[l31][tb0 + tau*16 + hi*8 .. +7]
        bf16x8 vf0 = *(const bf16x8*)&Vt[l31][tb0 + hi * 8];
        bf16x8 vf1 = *(const bf16x8*)&Vt[l31][tb0 + 16 + hi * 8];

        oacc0 = __builtin_amdgcn_mfma_f32_32x32x16_bf16(pa0, vf0, oacc0, 0, 0, 0);
        oacc0 = __builtin_amdgcn_mfma_f32_32x32x16_bf16(pa1, vf1, oacc0, 0, 0, 0);

        // ============ stile 1 ============
        cf = __builtin_amdgcn_mfma_f32_32x32x16_bf16(kf0, qf10, z16, 0, 0, 0);
        cf = __builtin_amdgcn_mfma_f32_32x32x16_bf16(kf1, qf11, cf, 0, 0, 0);

        a0 = pgrp<0>(cf, u0, mk0, lp1);
        a1 = pgrp<1>(cf, u1, mk1, lp1);
        a2 = pgrp<2>(cf, u2, mk2, lp1);
        a3 = pgrp<3>(cf, u3, mk3, lp1);

        bf16x8 pb0, pb1;
        frags(a0, a1, a2, a3, pb0, pb1);

        oacc1 = __builtin_amdgcn_mfma_f32_32x32x16_bf16(pb0, vf0, oacc1, 0, 0, 0);
        oacc1 = __builtin_amdgcn_mfma_f32_32x32x16_bf16(pb1, vf1, oacc1, 0, 0, 0);
    }

    // softmax denominators: hi-half reduce, then normalize + store
    lp0 += __shfl_xor(lp0, 32);
    lp1 += __shfl_xor(lp1, 32);
    const float li0 = 1.0f / lp0;      // valid for s = sbase + l31
    const float li1 = 1.0f / lp1;      // valid for s = sbase + 32 + l31

    float* ob = out + (size_t)inst * SEQ * DH;
    #pragma unroll
    for (int r = 0; r < 16; ++r) {
        const int srow = (r & 3) + 8 * (r >> 2) + 4 * hi;
        float i0 = __shfl(li0, srow);  // 1/l for row srow lives in lane srow
        float i1 = __shfl(li1, srow);
        ob[(size_t)(sbase + srow) * DH + l31]      = oacc0[r] * i0;
        ob[(size_t)(sbase + 32 + srow) * DH + l31] = oacc1[r] * i1;
    }
}

extern "C" void kernel_launch(void* const* d_in, const int* in_sizes, int n_in,
                              void* d_out, int out_size, void* d_ws, size_t ws_size,
                              hipStream_t stream) {
    const float* q    = (const float*)d_in[0];
    const float* k    = (const float*)d_in[1];
    const float* v    = (const float*)d_in[2];
    const float* mask = (const float*)d_in[3];
    const float* tri  = (const float*)d_in[4];
    float* out = (float*)d_out;

    attn_mfma_kernel<<<dim3(256 * 4), dim3(256), 0, stream>>>(q, k, v, mask, tri, out);
}